// Round 4
// baseline (666.435 us; speedup 1.0000x reference)
//
#include <hip/hip_runtime.h>
#include <hip/hip_bf16.h>
#include <stdint.h>

// SparseGAT: h=xW; e=leakyrelu(h@a_src[src]+h@a_dst[dst]); softmax-ish per src;
// h' = seg_sum(e*h[dst], src)/(seg_sum(e,src)+EPS); elu.
// Detected (R3): inputs f32-stored, edges int64-stored, output f32.
// Runtime detect kept for robustness (flags[0]: f32 floats, flags[1]: int64 edges).

#define NN 100000
#define NE 1600000
#define DIM 128
#define ALPHA_ 0.2f
#define EPS_ 9e-15f

typedef short bf16x8 __attribute__((ext_vector_type(8)));
typedef float floatx4 __attribute__((ext_vector_type(4)));

static __device__ __forceinline__ float bflo(unsigned u){ return __uint_as_float(u << 16); }
static __device__ __forceinline__ float bfhi(unsigned u){ return __uint_as_float(u & 0xFFFF0000u); }
static __device__ __forceinline__ unsigned short f2bf(float f){
  unsigned b = __float_as_uint(f);
  unsigned r = (b + 0x7FFFu + ((b >> 16) & 1u)) >> 16;   // RNE
  return (unsigned short)r;
}

// flags[0]=1 if float arrays are f32-stored; flags[1]=1 if edge_index is int64-stored.
// Also converts attn -> attnb (bf16).
__global__ __launch_bounds__(256) void k_detect(const unsigned short* W, const unsigned* EI,
                                                const unsigned short* attn, int* flags,
                                                unsigned short* attnb){
  __shared__ int sh_f, sh_e;
  int tid = threadIdx.x;
  if (tid == 0){ sh_f = 0; sh_e = 0; }
  __syncthreads();
  // f32 detect: bf16-stored W (|W|<1) has bf16-exponent < 0x85 in every ushort;
  // f32 storage puts uniform mantissa bits in even ushorts -> ~48% exceed.
  for (int i = tid; i < 1024; i += 256){
    unsigned u = W[i];
    unsigned e = (u >> 7) & 0xFF;
    if (e >= 0x85) sh_f = 1;     // benign race, same value
  }
  // int64 detect: odd dwords all zero iff int64 (values < 2^31, nonneg)
  int any = 0;
  for (int k = tid; k < 2048; k += 256) any |= EI[2 * k + 1];
  atomicOr(&sh_e, any);
  __syncthreads();
  if (tid == 0){ flags[0] = sh_f; flags[1] = (sh_e == 0) ? 1 : 0; }
  __syncthreads();
  int fdt = sh_f;
  attnb[tid] = fdt ? f2bf(((const float*)attn)[tid]) : attn[tid];
}

__global__ __launch_bounds__(256) void k_init(int* cnt, float* rowsum, unsigned* gkey){
  int i = blockIdx.x * 256 + threadIdx.x;
  if (i < NN){ cnt[i] = 0; rowsum[i] = 0.f; }
  if (i == 0) gkey[0] = 0u;
}

// stage X as bf16 into Xb. One dword (2 elems) per thread.
__global__ __launch_bounds__(256) void k_prep(const void* X, const int* flags, unsigned* Xb){
  int i = blockIdx.x * 256 + threadIdx.x;     // 6.4M dwords
  if (flags[0]){
    const float* xf = (const float*)X;
    float v0 = xf[2 * i], v1 = xf[2 * i + 1];
    Xb[i] = (unsigned)f2bf(v0) | ((unsigned)f2bf(v1) << 16);
  } else {
    Xb[i] = ((const unsigned*)X)[i];
  }
}

__global__ __launch_bounds__(256) void k_transpose(const void* W, const int* flags,
                                                   unsigned short* Wt){
  int i = blockIdx.x * 256 + threadIdx.x;   // 16384 elems
  int k = i >> 7, n = i & 127;
  unsigned short v = flags[0] ? f2bf(((const float*)W)[i]) : ((const unsigned short*)W)[i];
  Wt[n * DIM + k] = v;
}

// h = x @ W via MFMA 16x16x32 bf16. Block=4 waves, 64 rows/block, full 128 cols.
__global__ __launch_bounds__(256) void k_gemm(const unsigned short* X, const unsigned short* Wt,
                                              unsigned short* H){
  int wid = threadIdx.x >> 6, lane = threadIdx.x & 63;
  int m = lane & 15, q = lane >> 4;
  int rb = blockIdx.x * 64 + wid * 16;
  int row = rb + m;
  bool rok = row < NN;
  floatx4 acc[8];
  #pragma unroll
  for (int t = 0; t < 8; t++){ acc[t][0]=0.f; acc[t][1]=0.f; acc[t][2]=0.f; acc[t][3]=0.f; }
  #pragma unroll
  for (int ki = 0; ki < 4; ki++){
    int k0 = ki * 32 + q * 8;
    bf16x8 a;
    #pragma unroll
    for (int j = 0; j < 8; j++) a[j] = 0;
    if (rok) a = *(const bf16x8*)(X + row * DIM + k0);
    #pragma unroll
    for (int t = 0; t < 8; t++){
      bf16x8 b = *(const bf16x8*)(Wt + (t * 16 + m) * DIM + k0);
      acc[t] = __builtin_amdgcn_mfma_f32_16x16x32_bf16(a, b, acc[t], 0, 0, 0);
    }
  }
  // C/D: col = t*16 + (lane&15), row = rb + q*4 + r
  #pragma unroll
  for (int t = 0; t < 8; t++){
    #pragma unroll
    for (int r = 0; r < 4; r++){
      int grow = rb + q * 4 + r;
      if (grow < NN) H[grow * DIM + t * 16 + m] = f2bf(acc[t][r]);
    }
  }
}

// s1[n]=h[n]·a_src, s2[n]=h[n]·a_dst; one wave per node, 2 dims/lane.
__global__ __launch_bounds__(256) void k_s12(const unsigned short* H, const unsigned short* attnb,
                                             float* s1, float* s2){
  int wid = threadIdx.x >> 6, lane = threadIdx.x & 63;
  int n = blockIdx.x * 4 + wid;
  const unsigned* h2 = (const unsigned*)H;
  const unsigned* a2 = (const unsigned*)attnb;
  unsigned hv = h2[n * 64 + lane];
  unsigned av = a2[lane];
  unsigned bv = a2[64 + lane];
  float h0 = bflo(hv), h1 = bfhi(hv);
  float v1 = h0 * bflo(av) + h1 * bfhi(av);
  float v2 = h0 * bflo(bv) + h1 * bfhi(bv);
  #pragma unroll
  for (int off = 32; off; off >>= 1){ v1 += __shfl_xor(v1, off); v2 += __shfl_xor(v2, off); }
  if (lane == 0){ s1[n] = v1; s2[n] = v2; }
}

static __device__ __forceinline__ void load_edge(const int* EI, const int* flags, int e,
                                                 int& s, int& d){
  if (flags[1]){
    const long long* E64 = (const long long*)EI;
    s = (int)E64[e];
    d = (int)E64[NE + e];
  } else {
    s = EI[e];
    d = EI[NE + e];
  }
}

// degree histogram + global max of leaky-relu edge values (monotone-uint atomicMax)
__global__ __launch_bounds__(256) void k_histmax(const int* EI, const int* flags,
                                                 const float* s1, const float* s2,
                                                 int* cnt, unsigned* gkey){
  int e = blockIdx.x * 256 + threadIdx.x;
  int s, d;
  load_edge(EI, flags, e, s, d);
  atomicAdd(&cnt[s], 1);
  float v = s1[s] + s2[d];
  float va = v > 0.f ? v : ALPHA_ * v;
  va = fmaxf(va, -3.0e38f);   // NaN-proof the max
  #pragma unroll
  for (int off = 32; off; off >>= 1){ float o = __shfl_xor(va, off); va = fmaxf(va, o); }
  __shared__ float wm[4];
  int lane = threadIdx.x & 63, wid = threadIdx.x >> 6;
  if (lane == 0) wm[wid] = va;
  __syncthreads();
  if (threadIdx.x == 0){
    float mx = fmaxf(fmaxf(wm[0], wm[1]), fmaxf(wm[2], wm[3]));
    unsigned u = __float_as_uint(mx);
    unsigned k = (u & 0x80000000u) ? ~u : (u | 0x80000000u);
    atomicMax(gkey, k);
  }
}

// exclusive scan of cnt -> rowptr, and cnt becomes the scatter cursor.
__global__ __launch_bounds__(1024) void k_scan(int* cnt, int* rowptr){
  __shared__ int wsum[16];
  __shared__ int ctot;
  int tid = threadIdx.x, lane = tid & 63, wid = tid >> 6;
  int running = 0;
  for (int base = 0; base < NN; base += 1024){
    int i = base + tid;
    int c = (i < NN) ? cnt[i] : 0;
    int incl = c;
    #pragma unroll
    for (int d = 1; d < 64; d <<= 1){
      int t = __shfl_up(incl, d);
      if (lane >= d) incl += t;
    }
    if (lane == 63) wsum[wid] = incl;
    __syncthreads();
    if (tid == 0){
      int a = 0;
      for (int w = 0; w < 16; w++){ int t = wsum[w]; wsum[w] = a; a += t; }
      ctot = a;
    }
    __syncthreads();
    int excl = running + wsum[wid] + incl - c;
    if (i < NN){ rowptr[i] = excl; cnt[i] = excl; }  // cnt reused as cursor
    running += ctot;
    __syncthreads();
  }
  if (tid == 0) rowptr[NN] = running;
}

// per-edge weight, rowsum, and CSR scatter of (dst, w)
__global__ __launch_bounds__(256) void k_scatter(const int* EI, const int* flags,
                                                 const float* s1, const float* s2,
                                                 const unsigned* gkey, int* cursor,
                                                 float* rowsum, int* sdst, float* sw){
  int e = blockIdx.x * 256 + threadIdx.x;
  int s, d;
  load_edge(EI, flags, e, s, d);
  float v = s1[s] + s2[d];
  float va = v > 0.f ? v : ALPHA_ * v;
  unsigned k = gkey[0];
  unsigned u = (k & 0x80000000u) ? (k ^ 0x80000000u) : ~k;
  float gm = __uint_as_float(u);
  float w = __expf(va - gm);
  atomicAdd(&rowsum[s], w);
  int pos = atomicAdd(&cursor[s], 1);
  sdst[pos] = d;
  sw[pos] = w;
}

// h'[n] = sum_e w*h[dst] / (rowsum+EPS); elu. One wave per node, 2 dims/lane.
// OUTPUT IS FLOAT32 (reference output dtype).
__global__ __launch_bounds__(256) void k_aggregate(const int* rowptr, const int* sdst,
                                                   const float* sw, const unsigned short* H,
                                                   const float* rowsum, float* out){
  int wid = threadIdx.x >> 6, lane = threadIdx.x & 63;
  int n = blockIdx.x * 4 + wid;
  int i0 = rowptr[n], i1 = rowptr[n + 1];
  const unsigned* h2 = (const unsigned*)H;
  float a0 = 0.f, a1 = 0.f;
  for (int i = i0; i < i1; i++){
    int d = sdst[i];
    float w = sw[i];
    unsigned hv = h2[d * 64 + lane];
    a0 += w * bflo(hv);
    a1 += w * bfhi(hv);
  }
  float r = rowsum[n] + EPS_;
  float p0 = a0 / r, p1 = a1 / r;
  float o0 = p0 > 0.f ? p0 : expm1f(p0);
  float o1 = p1 > 0.f ? p1 : expm1f(p1);
  float2* o2 = (float2*)out;
  o2[n * 64 + lane] = make_float2(o0, o1);
}

extern "C" void kernel_launch(void* const* d_in, const int* in_sizes, int n_in,
                              void* d_out, int out_size, void* d_ws, size_t ws_size,
                              hipStream_t stream){
  (void)in_sizes; (void)n_in; (void)out_size; (void)ws_size;
  const void* X    = d_in[0];
  const int*  EI   = (const int*)d_in[1];
  const void* W    = d_in[2];
  const void* attn = d_in[3];

  char* ws = (char*)d_ws;
  size_t off = 0;
  auto alloc = [&](size_t bytes) -> char* {
    char* p = ws + off;
    off += (bytes + 255) & ~(size_t)255;
    return p;
  };
  unsigned short* H      = (unsigned short*)alloc((size_t)NN * DIM * 2);   // 25.6 MB
  unsigned*       Xb     = (unsigned*)alloc((size_t)NN * DIM * 2);         // 25.6 MB (bf16 X)
  unsigned short* Wt     = (unsigned short*)alloc(DIM * DIM * 2);
  unsigned short* attnb  = (unsigned short*)alloc(256 * 2);
  int*            flags  = (int*)alloc(2 * 4);
  float*          s1     = (float*)alloc(NN * 4);
  float*          s2     = (float*)alloc(NN * 4);
  int*            cnt    = (int*)alloc(NN * 4);       // degree, then cursor
  int*            rowptr = (int*)alloc((NN + 1) * 4);
  float*          rowsum = (float*)alloc(NN * 4);
  unsigned*       gkey   = (unsigned*)alloc(4);
  int*            sdst   = (int*)alloc((size_t)NE * 4);                     // 6.4 MB
  float*          sw     = (float*)alloc((size_t)NE * 4);                   // 6.4 MB
  float*          outp   = (float*)d_out;

  k_detect<<<1, 256, 0, stream>>>((const unsigned short*)W, (const unsigned*)EI,
                                  (const unsigned short*)attn, flags, attnb);
  k_init<<<(NN + 255) / 256, 256, 0, stream>>>(cnt, rowsum, gkey);
  k_prep<<<NN * DIM / 2 / 256, 256, 0, stream>>>(X, flags, Xb);
  k_transpose<<<64, 256, 0, stream>>>(W, flags, Wt);
  k_gemm<<<(NN + 63) / 64, 256, 0, stream>>>((const unsigned short*)Xb, Wt, H);
  k_s12<<<NN / 4, 256, 0, stream>>>(H, attnb, s1, s2);
  k_histmax<<<NE / 256, 256, 0, stream>>>(EI, flags, s1, s2, cnt, gkey);
  k_scan<<<1, 1024, 0, stream>>>(cnt, rowptr);
  k_scatter<<<NE / 256, 256, 0, stream>>>(EI, flags, s1, s2, gkey, cnt, rowsum, sdst, sw);
  k_aggregate<<<NN / 4, 256, 0, stream>>>(rowptr, sdst, sw, H, rowsum, outp);
}